// Round 4
// baseline (3236.045 us; speedup 1.0000x reference)
//
#include <hip/hip_runtime.h>
#include <math.h>

// Problem constants
#define BATCH  16384
#define HID    4096
#define NCOLS  1536     // NUM_SUB * H * 2
#define NGRP   384      // NUM_SUB * H / RANK

// Gap-certification margin (score units). Fast-path worst-case score error
// ~2e-6 (bf16x3 truncation + fp32 accum + gumbel_f); 2e-5 is a ~5x margin on 2E.
#define GAP_MIN 2.0e-5f

typedef short bf16x8 __attribute__((ext_vector_type(8)));
typedef float f32x4  __attribute__((ext_vector_type(4)));

__device__ __forceinline__ unsigned short f2bf(float f) {
    unsigned int v = __float_as_uint(f);
    unsigned int r = (v + 0x7FFFu + ((v >> 16) & 1u)) >> 16;   // RNE
    return (unsigned short)r;
}
__device__ __forceinline__ float bf2f(unsigned short s) {
    return __uint_as_float(((unsigned int)s) << 16);
}

__device__ __forceinline__ int budget_of(float lat) {
    float un = rintf(lat * 512.0f);           // round-half-even like jnp.round
    un = fminf(fmaxf(un, 128.0f), 512.0f);
    return (int)un - 128;                     // 0..384
}

__device__ __forceinline__ double gumbel_d(float uu) {
    double v = (double)uu * (1.0 - 2.0e-6) + 1.0e-6;
    return -log(-log(v));
}

// fp32 gumbel accurate at both tails (Sterbenz + log1pf for u>0.5).
__device__ __forceinline__ float gumbel_f(float u) {
    float inner;
    if (u <= 0.5f) {
        float v = fmaf(u, 0.999998f, 1e-6f);
        inner = -logf(v);
    } else {
        float t1 = 1.0f - u;                          // exact
        float w  = fmaf(1e-6f, fmaf(2.0f, u, -1.0f), t1);
        inner = -log1pf(-w);
    }
    return -logf(inner);
}

__device__ __forceinline__ float score_f(float l0, float l1, float l2, float l3,
                                         float4 uv) {
    const float d0 = ((l0 + gumbel_f(uv.x)) - (l1 + gumbel_f(uv.y))) * 0.2f;
    const float d1 = ((l2 + gumbel_f(uv.z)) - (l3 + gumbel_f(uv.w))) * 0.2f;
    const float p0 = 1.0f / (1.0f + expf(-d0));
    const float p1 = 1.0f / (1.0f + expf(-d1));
    return 0.5f * (p0 + p1);
}

// ---------------------------------------------------------------------------
// Per-sample classification + trivial-output fill + compaction of interior rows.
__global__ __launch_bounds__(64)
void prefilter_kernel(const float* __restrict__ latency, float* __restrict__ out,
                      int* __restrict__ count, int* __restrict__ idx)
{
    const int b = blockIdx.x;
    const int t = threadIdx.x;
    const int budget = budget_of(latency[b]);
    float* obase = out + (size_t)b * 2048;

    const float4 ones = make_float4(1.f, 1.f, 1.f, 1.f);
    ((float4*)obase)[t]      = ones;   // prefix: layers 0..7 all ones
    ((float4*)obase)[t + 64] = ones;

    if (budget > 0 && budget < NGRP) {
        if (t == 0) { int s = atomicAdd(count, 1); idx[s] = b; }
    } else {
        const float K = (budget == 0) ? 0.0f : 1.0f;
#pragma unroll
        for (int j = 0; j < 6; ++j) {
            const int i = j * 64 + t;
            const int p = i * 4;             // p = l*64 + s*32 + h
            const int s = (p >> 5) & 1;
            const float v = s ? (1.0f - K) : K;
            ((float4*)(obase + 512))[i] = make_float4(v, v, v, v);
        }
    }
}

// ---------------------------------------------------------------------------
// Split compacted x rows into bf16 hi/mid (a = hi + mid + O(2^-18 a)).
__global__ __launch_bounds__(256)
void split_x_kernel(const float* __restrict__ x, const int* __restrict__ idx,
                    const int* __restrict__ count,
                    unsigned short* __restrict__ xhi, unsigned short* __restrict__ xmid)
{
    const int b = blockIdx.x;
    if (b >= *count) return;
    const int t = threadIdx.x;
    const int orig = idx[b];
    const float* xp = x + (size_t)orig * HID;
    unsigned short* hp = xhi + (size_t)b * HID;
    unsigned short* mp = xmid + (size_t)b * HID;
#pragma unroll
    for (int i = 0; i < 4; ++i) {
        const int e = i * 1024 + t * 4;
        const float4 v = *(const float4*)(xp + e);
        const unsigned short h0 = f2bf(v.x), h1 = f2bf(v.y);
        const unsigned short h2 = f2bf(v.z), h3 = f2bf(v.w);
        *(ushort4*)(hp + e) = make_ushort4(h0, h1, h2, h3);
        *(ushort4*)(mp + e) = make_ushort4(f2bf(v.x - bf2f(h0)), f2bf(v.y - bf2f(h1)),
                                           f2bf(v.z - bf2f(h2)), f2bf(v.w - bf2f(h3)));
    }
}

// Transpose W (4096x1536) -> WT (1536x4096) while splitting into bf16 hi/mid.
// k becomes the contiguous dim so B-fragments are ds_read_b128-able.
__global__ __launch_bounds__(256)
void split_wT_kernel(const float* __restrict__ W,
                     unsigned short* __restrict__ whiT, unsigned short* __restrict__ wmidT)
{
    __shared__ float tile[64][65];
    const int k0 = blockIdx.x * 64;
    const int n0 = blockIdx.y * 64;
    const int t  = threadIdx.x;
    const int kk = t >> 2, nc = (t & 3) * 16;
#pragma unroll
    for (int j = 0; j < 4; ++j) {
        const float4 v = *(const float4*)(W + (size_t)(k0 + kk) * NCOLS + n0 + nc + 4 * j);
        tile[kk][nc + 4 * j + 0] = v.x;
        tile[kk][nc + 4 * j + 1] = v.y;
        tile[kk][nc + 4 * j + 2] = v.z;
        tile[kk][nc + 4 * j + 3] = v.w;
    }
    __syncthreads();
    const int nn = t >> 2, kc = (t & 3) * 16;
    unsigned short hb[16], mb[16];
#pragma unroll
    for (int j = 0; j < 16; ++j) {
        const float f = tile[kc + j][nn];
        const unsigned short h = f2bf(f);
        hb[j] = h;
        mb[j] = f2bf(f - bf2f(h));
    }
    unsigned short* hp = whiT  + (size_t)(n0 + nn) * HID + k0 + kc;
    unsigned short* mp = wmidT + (size_t)(n0 + nn) * HID + k0 + kc;
#pragma unroll
    for (int j = 0; j < 4; ++j) {
        *(ushort4*)(hp + 4 * j) = make_ushort4(hb[4*j], hb[4*j+1], hb[4*j+2], hb[4*j+3]);
        *(ushort4*)(mp + 4 * j) = make_ushort4(mb[4*j], mb[4*j+1], mb[4*j+2], mb[4*j+3]);
    }
}

// ---------------------------------------------------------------------------
// bf16x3 MFMA GEMM (128x128 tile, BK=32, m97 structure) + fused score epilogue.
#define GLDS(g, l) __builtin_amdgcn_global_load_lds(                              \
    (const __attribute__((address_space(1))) unsigned int*)(g),                   \
    (__attribute__((address_space(3))) unsigned int*)(l), 16, 0, 0)

__global__ __launch_bounds__(256)
void gemm_mfma_kernel(const unsigned short* __restrict__ xhi,
                      const unsigned short* __restrict__ xmid,
                      const unsigned short* __restrict__ whiT,
                      const unsigned short* __restrict__ wmidT,
                      const float* __restrict__ bias, const float* __restrict__ u,
                      const int* __restrict__ idx, const int* __restrict__ count,
                      float* __restrict__ scoresf)
{
    // 32KB: Ahi | Amid | BhiT | BmidT, each 128x32 bf16 (4096 shorts), unpadded
    // (global_load_lds requires contiguous lane order). Reused as epilogue scratch.
    __shared__ __align__(16) unsigned short smem[16384];
    __shared__ int rid[128];

    const int cnt  = *count;
    const int row0 = blockIdx.y * 128;
    if (row0 >= cnt) return;
    const int col0 = blockIdx.x * 128;
    const int t    = threadIdx.x;
    const int lane = t & 63, wid = t >> 6;
    const int wr = wid >> 1, wc = wid & 1;      // 2x2 wave grid, 64x64 each

    if (t < 128) rid[t] = idx[min(row0 + t, cnt - 1)];

    // staging: tile = 512 chunks of 16B; chunk c = i*256+t -> row c>>2, kcol (c&3)*8
    const int r  = t >> 2;
    const int kc = (t & 3) * 8;
    const unsigned short* gah = xhi   + (size_t)(row0 + r) * HID + kc;
    const unsigned short* gam = xmid  + (size_t)(row0 + r) * HID + kc;
    const unsigned short* gbh = whiT  + (size_t)(col0 + r) * HID + kc;
    const unsigned short* gbm = wmidT + (size_t)(col0 + r) * HID + kc;
    const size_t rstep = (size_t)64 * HID;      // chunk i=1: +64 rows

    const int wbase = (t & ~63) * 8;            // wave-uniform LDS base (shorts)
    unsigned short* lA0 = smem         + wbase;
    unsigned short* lA1 = smem + 4096  + wbase;
    unsigned short* lB0 = smem + 8192  + wbase;
    unsigned short* lB1 = smem + 12288 + wbase;

    const int q  = lane >> 4;
    const int lm = lane & 15;
    const int abase = (wr * 64 + lm) * 32 + q * 8;   // A frag: m=lane&15, k=q*8+j
    const int bbase = (wc * 64 + lm) * 32 + q * 8;   // B frag: n=lane&15, k=q*8+j

    f32x4 acc[4][4];
#pragma unroll
    for (int i = 0; i < 4; ++i)
#pragma unroll
        for (int j = 0; j < 4; ++j) acc[i][j] = 0;

    for (int kt = 0; kt < HID / 32; ++kt) {
        const int ko = kt * 32;
        GLDS(gah + ko, lA0);          GLDS(gah + ko + rstep, lA0 + 2048);
        GLDS(gam + ko, lA1);          GLDS(gam + ko + rstep, lA1 + 2048);
        GLDS(gbh + ko, lB0);          GLDS(gbh + ko + rstep, lB0 + 2048);
        GLDS(gbm + ko, lB1);          GLDS(gbm + ko + rstep, lB1 + 2048);
        __syncthreads();   // implies vmcnt(0): staged data visible

        bf16x8 ah[4], am[4], bh[4], bm[4];
#pragma unroll
        for (int f = 0; f < 4; ++f) {
            ah[f] = *(const bf16x8*)(smem         + abase + f * 512);
            am[f] = *(const bf16x8*)(smem + 4096  + abase + f * 512);
            bh[f] = *(const bf16x8*)(smem + 8192  + bbase + f * 512);
            bm[f] = *(const bf16x8*)(smem + 12288 + bbase + f * 512);
        }
#pragma unroll
        for (int i = 0; i < 4; ++i)
#pragma unroll
            for (int j = 0; j < 4; ++j) {
                acc[i][j] = __builtin_amdgcn_mfma_f32_16x16x32_bf16(ah[i], bh[j], acc[i][j], 0, 0, 0);
                acc[i][j] = __builtin_amdgcn_mfma_f32_16x16x32_bf16(ah[i], bm[j], acc[i][j], 0, 0, 0);
                acc[i][j] = __builtin_amdgcn_mfma_f32_16x16x32_bf16(am[i], bh[j], acc[i][j], 0, 0, 0);
            }
        __syncthreads();   // all reads done before next overwrite
    }

    // Epilogue: per-wave LDS transpose of C fragments (C-layout: col=lane&15,
    // row=q*4+reg) -> 4-col group reads -> gumbel-softmax score -> scoresf.
    float* epw = (float*)smem + wid * 1088;     // 16 rows x 68 cols per wave
    const int gg0 = (col0 + wc * 64) >> 2;
    for (int fm = 0; fm < 4; ++fm) {
#pragma unroll
        for (int fn = 0; fn < 4; ++fn)
#pragma unroll
            for (int rr = 0; rr < 4; ++rr)
                epw[(q * 4 + rr) * 68 + fn * 16 + lm] = acc[fm][fn][rr];
        __syncthreads();
#pragma unroll
        for (int i = 0; i < 4; ++i) {
            const int cell = lane + 64 * i;       // 256 cells: 16 rows x 16 groups
            const int rw = cell & 15;
            const int gl = cell >> 4;
            const float4 lv = *(const float4*)&epw[rw * 68 + gl * 4];
            const int rloc = wr * 64 + fm * 16 + rw;
            const int orig = rid[rloc];
            const int gg = gg0 + gl;
            const float4 bsv = *(const float4*)(bias + 4 * gg);
            const float4 uv  = *(const float4*)(u + (size_t)orig * NCOLS + 4 * gg);
            scoresf[(size_t)(row0 + rloc) * NGRP + gg] =
                score_f(lv.x + bsv.x, lv.y + bsv.y, lv.z + bsv.z, lv.w + bsv.w, uv);
        }
        __syncthreads();
    }
}

// ---------------------------------------------------------------------------
// Fallback fp32 GEMM (round-3, proven) — used only if ws_size is too small.
__global__ __launch_bounds__(256)
void gemm32_kernel(const float* __restrict__ x, const float* __restrict__ W,
                   const float* __restrict__ bias, const float* __restrict__ u,
                   const int* __restrict__ idx, const int* __restrict__ count,
                   float* __restrict__ scoresf)
{
    __shared__ float As[16][132];
    __shared__ float Bs[16][132];
    __shared__ int   rid[128];

    const int cnt  = *count;
    const int row0 = blockIdx.y * 128;
    if (row0 >= cnt) return;
    const int col0 = blockIdx.x * 128;
    const int t    = threadIdx.x;

    if (t < 128) rid[t] = idx[min(row0 + t, cnt - 1)];
    __syncthreads();

    const int ar  = t >> 2;
    const int akc = (t & 3) << 2;
    const int bkr = t >> 4;
    const int bnc = (t & 15) << 2;

    const size_t xoff0 = (size_t)rid[ar] * HID + akc;
    const size_t xoff1 = (size_t)rid[ar + 64] * HID + akc;
    const float* wp    = W + (size_t)bkr * NCOLS + col0 + bnc;

    const int ty = t >> 4;
    const int tx = t & 15;

    float acc[8][8] = {};

    float4 a0 = *(const float4*)(x + xoff0);
    float4 a1 = *(const float4*)(x + xoff1);
    float4 b0 = *(const float4*)(wp);
    float4 b1 = *(const float4*)(wp + 64);

    for (int k0 = 0; k0 < HID; k0 += 16) {
        __syncthreads();
        As[akc + 0][ar]      = a0.x; As[akc + 1][ar]      = a0.y;
        As[akc + 2][ar]      = a0.z; As[akc + 3][ar]      = a0.w;
        As[akc + 0][ar + 64] = a1.x; As[akc + 1][ar + 64] = a1.y;
        As[akc + 2][ar + 64] = a1.z; As[akc + 3][ar + 64] = a1.w;
        *(float4*)&Bs[bkr][bnc]      = b0;
        *(float4*)&Bs[bkr][bnc + 64] = b1;
        __syncthreads();

        if (k0 + 16 < HID) {
            a0 = *(const float4*)(x + xoff0 + k0 + 16);
            a1 = *(const float4*)(x + xoff1 + k0 + 16);
            b0 = *(const float4*)(wp + (size_t)(k0 + 16) * NCOLS);
            b1 = *(const float4*)(wp + (size_t)(k0 + 16) * NCOLS + 64);
        }

#pragma unroll
        for (int k = 0; k < 16; ++k) {
            const float4 af0 = *(const float4*)&As[k][ty * 8];
            const float4 af1 = *(const float4*)&As[k][ty * 8 + 4];
            const float4 bf0 = *(const float4*)&Bs[k][tx * 4];
            const float4 bf1 = *(const float4*)&Bs[k][tx * 4 + 64];
            const float a[8] = {af0.x, af0.y, af0.z, af0.w, af1.x, af1.y, af1.z, af1.w};
            const float b[8] = {bf0.x, bf0.y, bf0.z, bf0.w, bf1.x, bf1.y, bf1.z, bf1.w};
#pragma unroll
            for (int i = 0; i < 8; ++i)
#pragma unroll
                for (int j = 0; j < 8; ++j)
                    acc[i][j] = fmaf(a[i], b[j], acc[i][j]);
        }
    }

    const int g0 = (col0 >> 2) + tx;
    const int g1 = g0 + 16;
    const float4 bs0 = *(const float4*)(bias + 4 * g0);
    const float4 bs1 = *(const float4*)(bias + 4 * g1);
#pragma unroll
    for (int i = 0; i < 8; ++i) {
        const int rl   = ty * 8 + i;
        const int cr   = row0 + rl;
        const int orig = rid[rl];
        const float4 uv0 = *(const float4*)(u + (size_t)orig * NCOLS + 4 * g0);
        const float4 uv1 = *(const float4*)(u + (size_t)orig * NCOLS + 4 * g1);
        scoresf[(size_t)cr * NGRP + g0] =
            score_f(acc[i][0] + bs0.x, acc[i][1] + bs0.y,
                    acc[i][2] + bs0.z, acc[i][3] + bs0.w, uv0);
        scoresf[(size_t)cr * NGRP + g1] =
            score_f(acc[i][4] + bs1.x, acc[i][5] + bs1.y,
                    acc[i][6] + bs1.z, acc[i][7] + bs1.w, uv1);
    }
}

// ---------------------------------------------------------------------------
// fp32 selection with boundary-gap certification; flags close calls for fp64.
__global__ __launch_bounds__(384)
void select_fast(const float* __restrict__ scoresf, const float* __restrict__ latency,
                 const int* __restrict__ idx, const int* __restrict__ count,
                 float* __restrict__ out, int* __restrict__ ridx, int* __restrict__ rcount)
{
    const int b = blockIdx.x;
    if (b >= *count) return;
    const int t = threadIdx.x;
    const int orig = idx[b];

    __shared__ float sm[NGRP];
    __shared__ float bnd[2];
    __shared__ int   flag;
    const float sg = scoresf[(size_t)b * NGRP + t];
    sm[t] = sg;
    if (t == 0) flag = 0;
    const int budget = budget_of(latency[orig]);   // 1..383 here
    __syncthreads();

    int rank = 0;
#pragma unroll 8
    for (int j = 0; j < NGRP; ++j) {
        const float sj = sm[j];
        rank += (sj > sg || (sj == sg && j < t)) ? 1 : 0;
    }
    if (rank == budget - 1) bnd[0] = sg;   // min of kept set
    if (rank == budget)     bnd[1] = sg;   // max of dropped set
    __syncthreads();
    if (t == 0 && (bnd[0] - bnd[1] < GAP_MIN)) {
        flag = 1;
        ridx[atomicAdd(rcount, 1)] = orig;
    }
    __syncthreads();
    if (flag) return;

    const float keep = (rank < budget) ? 1.0f : 0.0f;
    float* p = out + (size_t)orig * 2048 + 512 + (size_t)(t >> 4) * 64;
    const int h2 = (t & 15) << 1;
    *(float2*)(p + h2)      = make_float2(keep, keep);
    *(float2*)(p + 32 + h2) = make_float2(1.0f - keep, 1.0f - keep);
}

// fp64 repair GEMM over flagged rows only.
__global__ __launch_bounds__(256)
void gemm64_repair(const float* __restrict__ x, const float* __restrict__ W,
                   const float* __restrict__ bias, const float* __restrict__ u,
                   const int* __restrict__ ridx, const int* __restrict__ rcount,
                   double* __restrict__ scores)
{
    __shared__ float As[16][36];
    __shared__ float Bs[16][68];
    __shared__ int   rid[32];

    const int cnt  = *rcount;
    const int row0 = blockIdx.y * 32;
    if (row0 >= cnt) return;
    const int col0 = blockIdx.x * 64;
    const int t    = threadIdx.x;

    if (t < 32) rid[t] = ridx[min(row0 + t, cnt - 1)];
    __syncthreads();

    const bool doA = (t < 128);
    const int ar  = t >> 2;
    const int akc = (t & 3) << 2;
    const int bkr = t >> 4;
    const int bnc = (t & 15) << 2;

    size_t xoff = 0;
    if (doA) xoff = (size_t)rid[ar] * HID + akc;
    const float* wp = W + (size_t)bkr * NCOLS + col0 + bnc;

    const int ty = t >> 4;
    const int tx = t & 15;

    double acc[2][4] = {};

    float4 a0 = make_float4(0, 0, 0, 0);
    if (doA) a0 = *(const float4*)(x + xoff);
    float4 b0 = *(const float4*)(wp);

    for (int k0 = 0; k0 < HID; k0 += 16) {
        __syncthreads();
        if (doA) {
            As[akc + 0][ar] = a0.x; As[akc + 1][ar] = a0.y;
            As[akc + 2][ar] = a0.z; As[akc + 3][ar] = a0.w;
        }
        *(float4*)&Bs[bkr][bnc] = b0;
        __syncthreads();
        if (k0 + 16 < HID) {
            if (doA) a0 = *(const float4*)(x + xoff + k0 + 16);
            b0 = *(const float4*)(wp + (size_t)(k0 + 16) * NCOLS);
        }
#pragma unroll
        for (int k = 0; k < 16; ++k) {
            const double a0d = (double)As[k][ty * 2];
            const double a1d = (double)As[k][ty * 2 + 1];
            const float4 bf  = *(const float4*)&Bs[k][tx * 4];
            const double bd[4] = {(double)bf.x, (double)bf.y, (double)bf.z, (double)bf.w};
#pragma unroll
            for (int j = 0; j < 4; ++j) {
                acc[0][j] = fma(a0d, bd[j], acc[0][j]);
                acc[1][j] = fma(a1d, bd[j], acc[1][j]);
            }
        }
    }

    const int g = (col0 >> 2) + tx;
    const double bs0 = (double)bias[4 * g + 0];
    const double bs1 = (double)bias[4 * g + 1];
    const double bs2 = (double)bias[4 * g + 2];
    const double bs3 = (double)bias[4 * g + 3];
#pragma unroll
    for (int i = 0; i < 2; ++i) {
        const int rl   = ty * 2 + i;
        const int cr   = row0 + rl;
        const int orig = rid[rl];
        const float4 uv = *(const float4*)(u + (size_t)orig * NCOLS + 4 * g);
        const double l0 = acc[i][0] + bs0;
        const double l1 = acc[i][1] + bs1;
        const double l2 = acc[i][2] + bs2;
        const double l3 = acc[i][3] + bs3;
        const double d0 = ((l0 + gumbel_d(uv.x)) - (l1 + gumbel_d(uv.y))) / 5.0;
        const double d1 = ((l2 + gumbel_d(uv.z)) - (l3 + gumbel_d(uv.w))) / 5.0;
        const double p0 = 1.0 / (1.0 + exp(-d0));
        const double p1 = 1.0 / (1.0 + exp(-d1));
        scores[(size_t)cr * NGRP + g] = 0.5 * (p0 + p1);
    }
}

// fp64 selection for flagged rows.
__global__ __launch_bounds__(384)
void select_repair(const double* __restrict__ scores, const float* __restrict__ latency,
                   const int* __restrict__ ridx, const int* __restrict__ rcount,
                   float* __restrict__ out)
{
    const int b = blockIdx.x;
    if (b >= *rcount) return;
    const int t = threadIdx.x;
    const int orig = ridx[b];

    __shared__ double sm[NGRP];
    const double sg = scores[(size_t)b * NGRP + t];
    sm[t] = sg;
    const int budget = budget_of(latency[orig]);
    __syncthreads();

    int rank = 0;
#pragma unroll 8
    for (int j = 0; j < NGRP; ++j) {
        const double sj = sm[j];
        rank += (sj > sg || (sj == sg && j < t)) ? 1 : 0;
    }
    const float keep = (rank < budget) ? 1.0f : 0.0f;

    float* p = out + (size_t)orig * 2048 + 512 + (size_t)(t >> 4) * 64;
    const int h2 = (t & 15) << 1;
    *(float2*)(p + h2)      = make_float2(keep, keep);
    *(float2*)(p + 32 + h2) = make_float2(1.0f - keep, 1.0f - keep);
}

// ---------------------------------------------------------------------------
extern "C" void kernel_launch(void* const* d_in, const int* in_sizes, int n_in,
                              void* d_out, int out_size, void* d_ws, size_t ws_size,
                              hipStream_t stream) {
    const float* x       = (const float*)d_in[0];
    const float* latency = (const float*)d_in[1];
    const float* W       = (const float*)d_in[2];
    const float* bias    = (const float*)d_in[3];
    const float* u       = (const float*)d_in[4];
    float* out           = (float*)d_out;

    int* count  = (int*)d_ws;
    int* rcount = (int*)((char*)d_ws + 4);
    int* idx    = (int*)((char*)d_ws + 256);
    int* ridx   = (int*)((char*)d_ws + 256 + 65536);
    const size_t base0 = 131328;   // 256-aligned
    // MFMA path layout: xhi(134.2M) xmid(134.2M) whiT(12.6M) wmidT(12.6M) scoresf(25.2M)
    const size_t NEED = base0 + 2ull * 134217728ull + 2ull * 12582912ull + 25165824ull;

    hipMemsetAsync(d_ws, 0, 256, stream);
    prefilter_kernel<<<BATCH, 64, 0, stream>>>(latency, out, count, idx);

    if (ws_size >= NEED) {
        unsigned short* xhi   = (unsigned short*)((char*)d_ws + base0);
        unsigned short* xmid  = (unsigned short*)((char*)d_ws + base0 + 134217728ull);
        unsigned short* whiT  = (unsigned short*)((char*)d_ws + base0 + 268435456ull);
        unsigned short* wmidT = (unsigned short*)((char*)d_ws + base0 + 281018368ull);
        float*  scoresf       = (float*)((char*)d_ws + base0 + 293601280ull);
        double* scores64      = (double*)((char*)d_ws + base0);  // alias xhi (dead after GEMM)

        split_x_kernel<<<BATCH, 256, 0, stream>>>(x, idx, count, xhi, xmid);
        split_wT_kernel<<<dim3(64, 24), 256, 0, stream>>>(W, whiT, wmidT);
        gemm_mfma_kernel<<<dim3(NCOLS / 128, BATCH / 128), 256, 0, stream>>>(
            xhi, xmid, whiT, wmidT, bias, u, idx, count, scoresf);
        select_fast<<<BATCH, NGRP, 0, stream>>>(scoresf, latency, idx, count, out, ridx, rcount);
        gemm64_repair<<<dim3(NCOLS / 64, BATCH / 32), 256, 0, stream>>>(
            x, W, bias, u, ridx, rcount, scores64);
        select_repair<<<BATCH, NGRP, 0, stream>>>(scores64, latency, ridx, rcount, out);
    } else {
        // Round-3 fallback (ws >= ~50.5MB, proven)
        float*  scoresf  = (float*)((char*)d_ws + base0);
        double* scores64 = (double*)((char*)d_ws + base0);   // aliased, disjoint lifetime
        gemm32_kernel<<<dim3(NCOLS / 128, BATCH / 128), 256, 0, stream>>>(
            x, W, bias, u, idx, count, scoresf);
        select_fast<<<BATCH, NGRP, 0, stream>>>(scoresf, latency, idx, count, out, ridx, rcount);
        gemm64_repair<<<dim3(NCOLS / 64, BATCH / 32), 256, 0, stream>>>(
            x, W, bias, u, ridx, rcount, scores64);
        select_repair<<<BATCH, NGRP, 0, stream>>>(scores64, latency, ridx, rcount, out);
    }
}